// Round 1
// baseline (1304.236 us; speedup 1.0000x reference)
//
#include <hip/hip_runtime.h>
#include <hip/hip_bf16.h>
#include <math.h>

typedef __bf16 bf16x8 __attribute__((ext_vector_type(8)));
typedef float f32x4 __attribute__((ext_vector_type(4)));

#define NB 2
#define NS 1024
#define ND 1024
#define NH 8
#define NQK 512
#define NV 1024
#define DQK 64
#define DHV 128

// ---------------- f32 -> bf16 conversion (vectorized) ----------------
__global__ __launch_bounds__(256) void cvt_f32_bf16(const float* __restrict__ in,
                                                    __bf16* __restrict__ out, int n4) {
  int i = blockIdx.x * 256 + threadIdx.x;
  if (i >= n4) return;
  float4 v = ((const float4*)in)[i];
  __bf16 o[4];
  o[0] = (__bf16)v.x; o[1] = (__bf16)v.y; o[2] = (__bf16)v.z; o[3] = (__bf16)v.w;
  ((short4*)out)[i] = *(const short4*)o;
}

// ---------------- bf16 GEMM, C[M,N] = A[M,K] * B[N,K]^T, f32 out ----------------
// 128x128 tile, 4 waves (2x2 of 64x64), 16x16x32 MFMA, BK=32.
__global__ __launch_bounds__(256) void gemm_bt(const __bf16* __restrict__ A,
                                               const __bf16* __restrict__ Bm,
                                               float* __restrict__ C,
                                               int M, int N, int K) {
  __shared__ __bf16 smA[128][40];  // +8 pad: frag ds_read_b128 ~2-way banks
  __shared__ __bf16 smB[128][40];
  const int tid = threadIdx.x;
  const int m0 = blockIdx.y * 128;
  const int n0 = blockIdx.x * 128;
  const int wid = tid >> 6, lane = tid & 63;
  const int wm = (wid >> 1) * 64, wn = (wid & 1) * 64;
  const int fr = lane & 15;   // A-row / B-row (=C col) within 16
  const int kg = lane >> 4;   // k-group: holds k = kg*8 .. kg*8+7
  const int srow = tid >> 1;          // staging row 0..127
  const int scol = (tid & 1) * 16;    // staging col 0 or 16
  const __bf16* gA = A + (size_t)(m0 + srow) * K + scol;
  const __bf16* gB = Bm + (size_t)(n0 + srow) * K + scol;
  f32x4 acc[4][4] = {};
  for (int kt = 0; kt < K; kt += 32) {
    float4 a0 = *(const float4*)(gA + kt);
    float4 a1 = *(const float4*)(gA + kt + 8);
    float4 b0 = *(const float4*)(gB + kt);
    float4 b1 = *(const float4*)(gB + kt + 8);
    *(float4*)&smA[srow][scol]     = a0;
    *(float4*)&smA[srow][scol + 8] = a1;
    *(float4*)&smB[srow][scol]     = b0;
    *(float4*)&smB[srow][scol + 8] = b1;
    __syncthreads();
    bf16x8 af[4], bfv[4];
    #pragma unroll
    for (int f = 0; f < 4; ++f) {
      af[f]  = *(const bf16x8*)&smA[wm + f*16 + fr][kg*8];
      bfv[f] = *(const bf16x8*)&smB[wn + f*16 + fr][kg*8];
    }
    #pragma unroll
    for (int i = 0; i < 4; ++i)
      #pragma unroll
      for (int j = 0; j < 4; ++j)
        acc[i][j] = __builtin_amdgcn_mfma_f32_16x16x32_bf16(af[i], bfv[j], acc[i][j], 0, 0, 0);
    __syncthreads();
  }
  // C/D layout: col = lane&15, row = (lane>>4)*4 + reg
  const int orow = m0 + wm + kg * 4;
  const int ocol = n0 + wn + fr;
  #pragma unroll
  for (int i = 0; i < 4; ++i)
    #pragma unroll
    for (int j = 0; j < 4; ++j)
      #pragma unroll
      for (int r = 0; r < 4; ++r)
        C[(size_t)(orow + i*16 + r) * N + (ocol + j*16)] = acc[i][j][r];
}

// ---------------- i/f gate pre-activations (full f32) ----------------
__global__ __launch_bounds__(256) void ifgate_kernel(const float* __restrict__ x,
    const float* __restrict__ Wi, const float* __restrict__ bi,
    const float* __restrict__ Wf, const float* __restrict__ bf_,
    float* __restrict__ icap, float* __restrict__ flog) {
  const int row = blockIdx.x;        // 0..2047
  const int w = threadIdx.x >> 6;    // wave 0..3 -> heads w*2, w*2+1
  const int l = threadIdx.x & 63;
  const float* xr = x + (size_t)row * ND;
  float xv[16];
  #pragma unroll
  for (int t = 0; t < 16; ++t) xv[t] = xr[l + 64*t];
  for (int hh = 0; hh < 2; ++hh) {
    int h = w*2 + hh;
    const float* wi = Wi + (size_t)h * ND;
    const float* wf = Wf + (size_t)h * ND;
    float si = 0.f, sf = 0.f;
    #pragma unroll
    for (int t = 0; t < 16; ++t) {
      si += xv[t] * wi[l + 64*t];
      sf += xv[t] * wf[l + 64*t];
    }
    #pragma unroll
    for (int off = 32; off; off >>= 1) {
      si += __shfl_xor(si, off, 64);
      sf += __shfl_xor(sf, off, 64);
    }
    if (l == 0) {
      float ic = 15.f * tanhf((si + bi[h]) * (1.f/15.f));
      float fc = 15.f * tanhf((sf + bf_[h]) * (1.f/15.f));
      // log_sigmoid, numerically stable
      float fl = (fc >= 0.f) ? -log1pf(__expf(-fc)) : (fc - log1pf(__expf(fc)));
      icap[row*NH + h] = ic;
      flog[row*NH + h] = fl;
    }
  }
}

// ---------------- sequential mLSTM scan: one block per (b,h) ----------------
// thread: wave w (0..7), lane l. j = w*16 + (l&15) in 0..127 (v-dim),
// dg = l>>4 in 0..3 -> holds C[dg*16 .. dg*16+15][j] and n[dg*16..+15].
__global__ __launch_bounds__(512) void scan_kernel(const float* __restrict__ P,
    const float* __restrict__ icap, const float* __restrict__ flog,
    float* __restrict__ hbuf) {
  const int bh = blockIdx.x;          // 0..15
  const int b = bh >> 3, h = bh & 7;
  const int tid = threadIdx.x;
  const int w = tid >> 6, l = tid & 63;
  const int j = w * 16 + (l & 15);
  const int dg = l >> 4;
  const int dbase = dg * 16;
  float Creg[16], nreg[16];
  #pragma unroll
  for (int r = 0; r < 16; ++r) { Creg[r] = 0.f; nreg[r] = 0.f; }
  float m = 0.f;
  const int PS = NQK + NQK + NV + NV;  // 3072
  const float* qp = P + (size_t)(b*NS) * PS + h*DQK + dbase;
  const float* kp = qp + NQK;
  const float* vp = P + (size_t)(b*NS) * PS + 2*NQK + h*DHV + j;
  const float* ip = icap + b*NS*NH + h;
  const float* fp = flog + b*NS*NH + h;
  float* hp = hbuf + (size_t)(b*NS) * NV + h*DHV + j;
  for (int s = 0; s < NS; ++s) {
    float it = ip[s*NH];
    float ft = fp[s*NH];
    float4 q0 = *(const float4*)(qp + 0);
    float4 q1 = *(const float4*)(qp + 4);
    float4 q2 = *(const float4*)(qp + 8);
    float4 q3 = *(const float4*)(qp + 12);
    float4 k0 = *(const float4*)(kp + 0);
    float4 k1 = *(const float4*)(kp + 4);
    float4 k2 = *(const float4*)(kp + 8);
    float4 k3 = *(const float4*)(kp + 12);
    float vj = *vp;
    float qq[16] = {q0.x,q0.y,q0.z,q0.w,q1.x,q1.y,q1.z,q1.w,
                    q2.x,q2.y,q2.z,q2.w,q3.x,q3.y,q3.z,q3.w};
    float kk[16] = {k0.x,k0.y,k0.z,k0.w,k1.x,k1.y,k1.z,k1.w,
                    k2.x,k2.y,k2.z,k2.w,k3.x,k3.y,k3.z,k3.w};
    float m_new = fmaxf(ft + m, it);
    float fa = __expf(ft + m - m_new);
    float ia = __expf(it - m_new);
    float iv = ia * vj;
    float ph[4] = {0.f,0.f,0.f,0.f};
    float pn[4] = {0.f,0.f,0.f,0.f};
    #pragma unroll
    for (int r = 0; r < 16; ++r) {
      Creg[r] = fa * Creg[r] + iv * kk[r];
      nreg[r] = fa * nreg[r] + ia * kk[r];
      ph[r & 3] += qq[r] * Creg[r];
      pn[r & 3] += qq[r] * nreg[r];
    }
    float phs = (ph[0] + ph[1]) + (ph[2] + ph[3]);
    float pns = (pn[0] + pn[1]) + (pn[2] + pn[3]);
    phs *= 0.125f;  // DQK^-0.5 (linear, applied post-dot)
    pns *= 0.125f;
    phs += __shfl_xor(phs, 16, 64);
    phs += __shfl_xor(phs, 32, 64);
    pns += __shfl_xor(pns, 16, 64);
    pns += __shfl_xor(pns, 32, 64);
    float denom = fmaxf(fabsf(pns), __expf(-m_new)) + 1e-6f;
    if (dg == 0) hp[0] = phs / denom;
    m = m_new;
    qp += PS; kp += PS; vp += PS; hp += NV;
  }
}

// ---------------- per-(b,s,h) layernorm + output gate, write bf16 ----------------
__global__ __launch_bounds__(64) void lngate_kernel(const float* __restrict__ hbuf,
    const float* __restrict__ P, const float* __restrict__ gamma,
    __bf16* __restrict__ hout) {
  const int bsh = blockIdx.x;          // row*8 + h
  const int row = bsh >> 3, h = bsh & 7;
  const int l = threadIdx.x;
  const int PS = 3072;
  const float* hp = hbuf + (size_t)row*NV + h*DHV;
  float h0 = hp[l], h1 = hp[l+64];
  float sum = h0 + h1;
  #pragma unroll
  for (int off = 32; off; off >>= 1) sum += __shfl_xor(sum, off, 64);
  float mu = sum * (1.f/128.f);
  float d0 = h0 - mu, d1 = h1 - mu;
  float ss = d0*d0 + d1*d1;
  #pragma unroll
  for (int off = 32; off; off >>= 1) ss += __shfl_xor(ss, off, 64);
  float rstd = rsqrtf(ss * (1.f/128.f) + 1e-6f);
  const float* ogp = P + (size_t)row*PS + 2048 + h*DHV;
  const float* gp = gamma + h*DHV;
  float g0 = 1.f / (1.f + __expf(-ogp[l]));
  float g1 = 1.f / (1.f + __expf(-ogp[l+64]));
  hout[(size_t)row*NV + h*DHV + l]      = (__bf16)(d0 * rstd * gp[l]    * g0);
  hout[(size_t)row*NV + h*DHV + l + 64] = (__bf16)(d1 * rstd * gp[l+64] * g1);
}

extern "C" void kernel_launch(void* const* d_in, const int* in_sizes, int n_in,
                              void* d_out, int out_size, void* d_ws, size_t ws_size,
                              hipStream_t stream) {
  const float* x    = (const float*)d_in[0];
  const float* Wq   = (const float*)d_in[1];
  const float* Wk   = (const float*)d_in[2];
  const float* Wv   = (const float*)d_in[3];
  const float* Wog  = (const float*)d_in[4];
  const float* Wi   = (const float*)d_in[5];
  const float* bi   = (const float*)d_in[6];
  const float* Wf   = (const float*)d_in[7];
  const float* bf_  = (const float*)d_in[8];
  const float* gamma= (const float*)d_in[9];
  const float* Wout = (const float*)d_in[10];
  float* y = (float*)d_out;

  char* ws = (char*)d_ws;
  const size_t MB = 1u << 20;
  __bf16* xb    = (__bf16*)(ws + 0);        // 2048x1024 bf16   (4 MB)
  __bf16* Wb    = (__bf16*)(ws + 4*MB);     // 3072x1024 bf16   (6 MB) [Wq|Wk|Wv|Wog]
  __bf16* Wob   = (__bf16*)(ws + 10*MB);    // 1024x1024 bf16   (2 MB)
  float*  P     = (float*) (ws + 12*MB);    // 2048x3072 f32    (24 MB) [q|k|v|og]
  float*  icap  = (float*) (ws + 36*MB);    // 2048x8 f32
  float*  flog  = (float*) (ws + 36*MB + 65536);
  float*  hbuf  = (float*) (ws + 37*MB);    // 2048x1024 f32    (8 MB)
  __bf16* houtb = (__bf16*)(ws + 45*MB);    // 2048x1024 bf16   (4 MB)

  // conversions
  cvt_f32_bf16<<<(2048*1024/4 + 255)/256, 256, 0, stream>>>(x, xb, 2048*1024/4);
  cvt_f32_bf16<<<(512*1024/4 + 255)/256, 256, 0, stream>>>(Wq, Wb + 0,          512*1024/4);
  cvt_f32_bf16<<<(512*1024/4 + 255)/256, 256, 0, stream>>>(Wk, Wb + 512*1024,   512*1024/4);
  cvt_f32_bf16<<<(1024*1024/4 + 255)/256, 256, 0, stream>>>(Wv, Wb + 1024*1024, 1024*1024/4);
  cvt_f32_bf16<<<(1024*1024/4 + 255)/256, 256, 0, stream>>>(Wog, Wb + 2048*1024, 1024*1024/4);
  cvt_f32_bf16<<<(1024*1024/4 + 255)/256, 256, 0, stream>>>(Wout, Wob, 1024*1024/4);

  // fused projection GEMM: P[2048,3072] = xb * Wb^T
  gemm_bt<<<dim3(3072/128, 2048/128), 256, 0, stream>>>(xb, Wb, P, 2048, 3072, 1024);

  // i/f gates in f32
  ifgate_kernel<<<2048, 256, 0, stream>>>(x, Wi, bi, Wf, bf_, icap, flog);

  // sequential recurrence: 16 chains
  scan_kernel<<<16, 512, 0, stream>>>(P, icap, flog, hbuf);

  // LN + gate -> bf16
  lngate_kernel<<<2048*8, 64, 0, stream>>>(hbuf, P, gamma, houtb);

  // y = hout * Wout^T
  gemm_bt<<<dim3(1024/128, 2048/128), 256, 0, stream>>>(houtb, Wob, y, 2048, 1024, 1024);
}

// Round 2
// 218.362 us; speedup vs baseline: 5.9728x; 5.9728x over previous
//
#include <hip/hip_runtime.h>
#include <hip/hip_bf16.h>
#include <math.h>

typedef __bf16 bf16x8 __attribute__((ext_vector_type(8)));
typedef float f32x4 __attribute__((ext_vector_type(4)));

#define NB 2
#define NS 1024
#define ND 1024
#define NH 8
#define NQK 512
#define NV 1024
#define DQK 64
#define DHV 128
#define CHUNK 64
#define NCHUNK 16
#define NBH 16

// ---------------- f32 -> bf16 conversion (vectorized) ----------------
__global__ __launch_bounds__(256) void cvt_f32_bf16(const float* __restrict__ in,
                                                    __bf16* __restrict__ out, int n4) {
  int i = blockIdx.x * 256 + threadIdx.x;
  if (i >= n4) return;
  float4 v = ((const float4*)in)[i];
  __bf16 o[4];
  o[0] = (__bf16)v.x; o[1] = (__bf16)v.y; o[2] = (__bf16)v.z; o[3] = (__bf16)v.w;
  ((short4*)out)[i] = *(const short4*)o;
}

// ---------------- bf16 GEMM, C[M,N] = A[M,K] * B[N,K]^T, f32 out ----------------
__global__ __launch_bounds__(256) void gemm_bt(const __bf16* __restrict__ A,
                                               const __bf16* __restrict__ Bm,
                                               float* __restrict__ C,
                                               int M, int N, int K) {
  __shared__ __bf16 smA[128][40];
  __shared__ __bf16 smB[128][40];
  const int tid = threadIdx.x;
  const int m0 = blockIdx.y * 128;
  const int n0 = blockIdx.x * 128;
  const int wid = tid >> 6, lane = tid & 63;
  const int wm = (wid >> 1) * 64, wn = (wid & 1) * 64;
  const int fr = lane & 15;
  const int kg = lane >> 4;
  const int srow = tid >> 1;
  const int scol = (tid & 1) * 16;
  const __bf16* gA = A + (size_t)(m0 + srow) * K + scol;
  const __bf16* gB = Bm + (size_t)(n0 + srow) * K + scol;
  f32x4 acc[4][4] = {};
  for (int kt = 0; kt < K; kt += 32) {
    float4 a0 = *(const float4*)(gA + kt);
    float4 a1 = *(const float4*)(gA + kt + 8);
    float4 b0 = *(const float4*)(gB + kt);
    float4 b1 = *(const float4*)(gB + kt + 8);
    *(float4*)&smA[srow][scol]     = a0;
    *(float4*)&smA[srow][scol + 8] = a1;
    *(float4*)&smB[srow][scol]     = b0;
    *(float4*)&smB[srow][scol + 8] = b1;
    __syncthreads();
    bf16x8 af[4], bfv[4];
    #pragma unroll
    for (int f = 0; f < 4; ++f) {
      af[f]  = *(const bf16x8*)&smA[wm + f*16 + fr][kg*8];
      bfv[f] = *(const bf16x8*)&smB[wn + f*16 + fr][kg*8];
    }
    #pragma unroll
    for (int i = 0; i < 4; ++i)
      #pragma unroll
      for (int j = 0; j < 4; ++j)
        acc[i][j] = __builtin_amdgcn_mfma_f32_16x16x32_bf16(af[i], bfv[j], acc[i][j], 0, 0, 0);
    __syncthreads();
  }
  const int orow = m0 + wm + kg * 4;
  const int ocol = n0 + wn + fr;
  #pragma unroll
  for (int i = 0; i < 4; ++i)
    #pragma unroll
    for (int j = 0; j < 4; ++j)
      #pragma unroll
      for (int r = 0; r < 4; ++r)
        C[(size_t)(orow + i*16 + r) * N + (ocol + j*16)] = acc[i][j][r];
}

// ---------------- i/f gate pre-activations (full f32) ----------------
__global__ __launch_bounds__(256) void ifgate_kernel(const float* __restrict__ x,
    const float* __restrict__ Wi, const float* __restrict__ bi,
    const float* __restrict__ Wf, const float* __restrict__ bf_,
    float* __restrict__ icap, float* __restrict__ flog) {
  const int row = blockIdx.x;
  const int w = threadIdx.x >> 6;
  const int l = threadIdx.x & 63;
  const float* xr = x + (size_t)row * ND;
  float xv[16];
  #pragma unroll
  for (int t = 0; t < 16; ++t) xv[t] = xr[l + 64*t];
  for (int hh = 0; hh < 2; ++hh) {
    int h = w*2 + hh;
    const float* wi = Wi + (size_t)h * ND;
    const float* wf = Wf + (size_t)h * ND;
    float si = 0.f, sf = 0.f;
    #pragma unroll
    for (int t = 0; t < 16; ++t) {
      si += xv[t] * wi[l + 64*t];
      sf += xv[t] * wf[l + 64*t];
    }
    #pragma unroll
    for (int off = 32; off; off >>= 1) {
      si += __shfl_xor(si, off, 64);
      sf += __shfl_xor(sf, off, 64);
    }
    if (l == 0) {
      float ic = 15.f * tanhf((si + bi[h]) * (1.f/15.f));
      float fc = 15.f * tanhf((sf + bf_[h]) * (1.f/15.f));
      float fl = (fc >= 0.f) ? -log1pf(__expf(-fc)) : (fc - log1pf(__expf(fc)));
      icap[row*NH + h] = ic;
      flog[row*NH + h] = fl;
    }
  }
}

// ---------------- gate scan: per (b,h), chunked cumsum/cummax ----------------
// outputs per (bh,t): g = i - B, a = max(m0, cummax g), m = B + a; per (bh,c): m0 (chunk-start carry)
__global__ __launch_bounds__(64) void gates_kernel(const float* __restrict__ icap,
    const float* __restrict__ flog, float* __restrict__ g_g, float* __restrict__ a_g,
    float* __restrict__ m_g, float* __restrict__ m0g) {
  const int bh = blockIdx.x;
  const int b = bh >> 3, h = bh & 7;
  const int l = threadIdx.x;
  float m0 = 0.f;
  for (int c = 0; c < NCHUNK; ++c) {
    const int t = c*CHUNK + l;
    const int row = b*NS + t;
    float B = flog[row*NH + h];
    float iv = icap[row*NH + h];
    #pragma unroll
    for (int d = 1; d < 64; d <<= 1) {
      float o = __shfl_up(B, d, 64);
      if (l >= d) B += o;
    }
    float g = iv - B;
    float cm = g;
    #pragma unroll
    for (int d = 1; d < 64; d <<= 1) {
      float o = __shfl_up(cm, d, 64);
      if (l >= d) cm = fmaxf(cm, o);
    }
    float a = fmaxf(m0, cm);
    float m = B + a;
    const int idx = bh*NS + t;
    g_g[idx] = g; a_g[idx] = a; m_g[idx] = m;
    if (l == 0) m0g[bh*NCHUNK + c] = m0;
    m0 = __shfl(m, 63, 64);
  }
}

// ---------------- per-chunk state contribution U = K^T diag(w) V, u_n = K^T w ----------------
__global__ __launch_bounds__(256) void u_kernel(const float* __restrict__ P,
    const float* __restrict__ g_g, const float* __restrict__ a_g,
    float* __restrict__ Ug, float* __restrict__ Ung) {
  __shared__ float kw[64][68];
  __shared__ float vsm[64][132];
  const int task = blockIdx.x;
  const int bh = task >> 4, c = task & 15;
  const int b = bh >> 3, h = bh & 7;
  const int t = threadIdx.x;
  const int row0 = b*NS + c*CHUNK;
  const float aL = a_g[bh*NS + c*CHUNK + 63];
  const int srow = t >> 2, sq = t & 3;
  const float w = __expf(g_g[bh*NS + c*CHUNK + srow] - aL);
  const float* kr = P + (size_t)(row0 + srow)*3072 + NQK + h*DQK + sq*16;
  #pragma unroll
  for (int q4 = 0; q4 < 4; ++q4) {
    float4 kv = *(const float4*)(kr + q4*4);
    float4 kk; kk.x = w*kv.x; kk.y = w*kv.y; kk.z = w*kv.z; kk.w = w*kv.w;
    *(float4*)&kw[srow][sq*16 + q4*4] = kk;
  }
  const float* vr = P + (size_t)(row0 + srow)*3072 + 2*NQK + h*DHV + sq*32;
  #pragma unroll
  for (int q4 = 0; q4 < 8; ++q4)
    *(float4*)&vsm[srow][sq*32 + q4*4] = *(const float4*)(vr + q4*4);
  __syncthreads();
  const int rg = t >> 4, jg = t & 15;
  const int r0 = rg*4, u0 = jg*8;
  float acc[4][8] = {};
  float kn[4] = {0.f,0.f,0.f,0.f};
  for (int s = 0; s < 64; ++s) {
    f32x4 kv = *(f32x4*)&kw[s][r0];
    f32x4 va = *(f32x4*)&vsm[s][u0];
    f32x4 vb = *(f32x4*)&vsm[s][u0+4];
    #pragma unroll
    for (int r = 0; r < 4; ++r) {
      float kvr = kv[r];
      kn[r] += kvr;
      #pragma unroll
      for (int uu = 0; uu < 4; ++uu) {
        acc[r][uu]   += kvr * va[uu];
        acc[r][uu+4] += kvr * vb[uu];
      }
    }
  }
  float* ub = Ug + (size_t)task * 64 * 128;
  #pragma unroll
  for (int r = 0; r < 4; ++r) {
    *(float4*)(ub + (r0+r)*128 + u0)     = *(float4*)&acc[r][0];
    *(float4*)(ub + (r0+r)*128 + u0 + 4) = *(float4*)&acc[r][4];
  }
  if (jg == 0) {
    #pragma unroll
    for (int r = 0; r < 4; ++r) Ung[task*64 + r0 + r] = kn[r];
  }
}

// ---------------- inter-chunk state prefix scan (elementwise, 16 steps) ----------------
__global__ __launch_bounds__(512) void statescan_kernel(const float* __restrict__ Ug,
    const float* __restrict__ Ung, const float* __restrict__ m0g,
    const float* __restrict__ a_g, float* __restrict__ C0g, float* __restrict__ n0g) {
  const int bx = blockIdx.x;
  const int bh = bx >> 4, part = bx & 15;
  const int e = part*512 + threadIdx.x;
  float scale[NCHUNK];
  #pragma unroll
  for (int c = 0; c < NCHUNK; ++c)
    scale[c] = __expf(m0g[bh*NCHUNK + c] - a_g[bh*NS + c*CHUNK + 63]);
  float val = 0.f;
  for (int c = 0; c < NCHUNK; ++c) {
    size_t idx = ((size_t)(bh*NCHUNK + c))*8192 + e;
    C0g[idx] = val;
    val = scale[c]*val + Ug[idx];
  }
  if (part == 0 && threadIdx.x < 64) {
    float nv = 0.f;
    for (int c = 0; c < NCHUNK; ++c) {
      int idx = (bh*NCHUNK + c)*64 + threadIdx.x;
      n0g[idx] = nv;
      nv = scale[c]*nv + Ung[idx];
    }
  }
}

// ---------------- intra-chunk attention + inter term + denom + LN + gate ----------------
__global__ __launch_bounds__(256) void intra_kernel(const float* __restrict__ P,
    const float* __restrict__ g_g, const float* __restrict__ a_g,
    const float* __restrict__ m_g, const float* __restrict__ m0g,
    const float* __restrict__ C0g, const float* __restrict__ n0g,
    const float* __restrict__ gamma, __bf16* __restrict__ hout) {
  __shared__ float sm[13440];
  float* qs = sm;             // [64][68]
  float* ks = sm + 4352;      // [64][68]
  float* Ps = sm + 8704;      // [64][68]
  float* vs = sm;             // [64][132], overlaps qs+ks after phase A
  float* g_l = sm + 13056;
  float* a_l = g_l + 64;
  float* m_l = a_l + 64;
  float* cI  = m_l + 64;
  float* qnA = cI + 64;
  float* qnB = qnA + 64;
  const int task = blockIdx.x;
  const int bh = task >> 4, c = task & 15;
  const int b = bh >> 3, h = bh & 7;
  const int t = threadIdx.x;
  const int row0 = b*NS + c*CHUNK;
  // stage q (x0.125) and k
  {
    const int srow = t >> 2, sq = t & 3;
    const float* qr = P + (size_t)(row0 + srow)*3072 + h*DQK + sq*16;
    #pragma unroll
    for (int q4 = 0; q4 < 4; ++q4) {
      float4 qv = *(const float4*)(qr + q4*4);
      qv.x *= 0.125f; qv.y *= 0.125f; qv.z *= 0.125f; qv.w *= 0.125f;
      *(float4*)&qs[srow*68 + sq*16 + q4*4] = qv;
      *(float4*)&ks[srow*68 + sq*16 + q4*4] = *(const float4*)(qr + NQK + q4*4);
    }
  }
  const float m0 = m0g[bh*NCHUNK + c];
  if (t < 64) {
    float gv = g_g[bh*NS + c*CHUNK + t];
    float av = a_g[bh*NS + c*CHUNK + t];
    float mv = m_g[bh*NS + c*CHUNK + t];
    g_l[t] = gv; a_l[t] = av; m_l[t] = mv;
    cI[t] = __expf(m0 - av);
  }
  __syncthreads();
  const int jg = t >> 4, lo = t & 15;
  const int j0 = jg*4;
  // Phase A: S[j][s] = (q.k)
  const int s0 = lo*4;
  float s16[4][4] = {};
  for (int d0 = 0; d0 < 64; d0 += 4) {
    f32x4 qv[4], kv[4];
    #pragma unroll
    for (int r = 0; r < 4; ++r) qv[r] = *(f32x4*)&qs[(j0+r)*68 + d0];
    #pragma unroll
    for (int r2 = 0; r2 < 4; ++r2) kv[r2] = *(f32x4*)&ks[(s0+r2)*68 + d0];
    #pragma unroll
    for (int r = 0; r < 4; ++r)
      #pragma unroll
      for (int r2 = 0; r2 < 4; ++r2)
        s16[r][r2] += qv[r][0]*kv[r2][0] + qv[r][1]*kv[r2][1]
                    + qv[r][2]*kv[r2][2] + qv[r][3]*kv[r2][3];
  }
  // weights + row sums + write P
  float rs[4];
  #pragma unroll
  for (int r = 0; r < 4; ++r) {
    const int j = j0 + r;
    const float aj = a_l[j];
    float pv[4];
    rs[r] = 0.f;
    #pragma unroll
    for (int r2 = 0; r2 < 4; ++r2) {
      const int s = s0 + r2;
      float w = (s <= j) ? __expf(g_l[s] - aj) : 0.f;
      float p = s16[r][r2] * w;
      rs[r] += p;
      pv[r2] = p;
    }
    *(float4*)&Ps[j*68 + s0] = *(float4*)pv;
  }
  #pragma unroll
  for (int r = 0; r < 4; ++r) {
    #pragma unroll
    for (int off = 1; off < 16; off <<= 1) rs[r] += __shfl_xor(rs[r], off, 64);
  }
  if (lo == 0) {
    #pragma unroll
    for (int r = 0; r < 4; ++r) qnA[j0 + r] = rs[r];
  }
  // Phase A2: inter term from C0, n0 (qs still live)
  const int u0 = lo*8;
  float acc[4][8] = {};
  float qn_i[4] = {0.f,0.f,0.f,0.f};
  const float* c0base = C0g + (size_t)task * 8192;
  const float* n0base = n0g + task * 64;
  for (int d = 0; d < 64; ++d) {
    float qd[4];
    #pragma unroll
    for (int r = 0; r < 4; ++r) qd[r] = qs[(j0+r)*68 + d];
    f32x4 ca = *(const f32x4*)(c0base + d*128 + u0);
    f32x4 cb = *(const f32x4*)(c0base + d*128 + u0 + 4);
    float nd = n0base[d];
    #pragma unroll
    for (int r = 0; r < 4; ++r) {
      qn_i[r] += qd[r]*nd;
      #pragma unroll
      for (int uu = 0; uu < 4; ++uu) {
        acc[r][uu]   += qd[r]*ca[uu];
        acc[r][uu+4] += qd[r]*cb[uu];
      }
    }
  }
  #pragma unroll
  for (int r = 0; r < 4; ++r) {
    const float ci = cI[j0 + r];
    #pragma unroll
    for (int uu = 0; uu < 8; ++uu) acc[r][uu] *= ci;
    qn_i[r] *= ci;
  }
  if (lo == 0) {
    #pragma unroll
    for (int r = 0; r < 4; ++r) qnB[j0 + r] = qn_i[r];
  }
  __syncthreads();
  // stage v over qs/ks
  {
    const int srow = t >> 2, sq = t & 3;
    const float* vr = P + (size_t)(row0 + srow)*3072 + 2*NQK + h*DHV + sq*32;
    #pragma unroll
    for (int q4 = 0; q4 < 8; ++q4)
      *(float4*)&vs[srow*132 + sq*32 + q4*4] = *(const float4*)(vr + q4*4);
  }
  __syncthreads();
  // Phase B: acc += P . V
  for (int ss = 0; ss < 64; ss += 4) {
    f32x4 pr[4];
    #pragma unroll
    for (int r = 0; r < 4; ++r) pr[r] = *(f32x4*)&Ps[(j0+r)*68 + ss];
    #pragma unroll
    for (int sr = 0; sr < 4; ++sr) {
      f32x4 va = *(f32x4*)&vs[(ss+sr)*132 + u0];
      f32x4 vb = *(f32x4*)&vs[(ss+sr)*132 + u0 + 4];
      #pragma unroll
      for (int r = 0; r < 4; ++r) {
        float p = pr[r][sr];
        #pragma unroll
        for (int uu = 0; uu < 4; ++uu) {
          acc[r][uu]   += p * va[uu];
          acc[r][uu+4] += p * vb[uu];
        }
      }
    }
  }
  // Epilogue: denom, LN over 128 (reduce across 16 lo-lanes), gate, bf16 out
  #pragma unroll
  for (int r = 0; r < 4; ++r) {
    const int j = j0 + r;
    float qn = qnA[j] + qnB[j];
    float denom = fmaxf(fabsf(qn), __expf(-m_l[j])) + 1e-6f;
    float rd = 1.f / denom;
    float hv[8];
    float sum = 0.f;
    #pragma unroll
    for (int uu = 0; uu < 8; ++uu) { hv[uu] = acc[r][uu]*rd; sum += hv[uu]; }
    #pragma unroll
    for (int off = 1; off < 16; off <<= 1) sum += __shfl_xor(sum, off, 64);
    float mu = sum * (1.f/128.f);
    float ss2 = 0.f;
    #pragma unroll
    for (int uu = 0; uu < 8; ++uu) { hv[uu] -= mu; ss2 += hv[uu]*hv[uu]; }
    #pragma unroll
    for (int off = 1; off < 16; off <<= 1) ss2 += __shfl_xor(ss2, off, 64);
    float rstd = rsqrtf(ss2 * (1.f/128.f) + 1e-6f);
    const float* ogp = P + (size_t)(row0 + j)*3072 + 2048 + h*DHV + u0;
    f32x4 oa = *(const f32x4*)ogp;
    f32x4 ob = *(const f32x4*)(ogp + 4);
    const float* gp = gamma + h*DHV + u0;
    f32x4 ga = *(const f32x4*)gp;
    f32x4 gb = *(const f32x4*)(gp + 4);
    __bf16 outv[8];
    #pragma unroll
    for (int uu = 0; uu < 4; ++uu) {
      float sg0 = 1.f/(1.f + __expf(-oa[uu]));
      float sg1 = 1.f/(1.f + __expf(-ob[uu]));
      outv[uu]   = (__bf16)(hv[uu]  * rstd * ga[uu] * sg0);
      outv[uu+4] = (__bf16)(hv[uu+4]* rstd * gb[uu] * sg1);
    }
    *(float4*)&hout[(size_t)(row0 + j)*NV + h*DHV + u0] = *(float4*)outv;
  }
}

extern "C" void kernel_launch(void* const* d_in, const int* in_sizes, int n_in,
                              void* d_out, int out_size, void* d_ws, size_t ws_size,
                              hipStream_t stream) {
  const float* x    = (const float*)d_in[0];
  const float* Wq   = (const float*)d_in[1];
  const float* Wk   = (const float*)d_in[2];
  const float* Wv   = (const float*)d_in[3];
  const float* Wog  = (const float*)d_in[4];
  const float* Wi   = (const float*)d_in[5];
  const float* bi   = (const float*)d_in[6];
  const float* Wf   = (const float*)d_in[7];
  const float* bf_  = (const float*)d_in[8];
  const float* gamma= (const float*)d_in[9];
  const float* Wout = (const float*)d_in[10];
  float* y = (float*)d_out;

  char* ws = (char*)d_ws;
  const size_t MB = 1u << 20;
  __bf16* xb   = (__bf16*)(ws + 0);          // 4 MB (dead after gemm1)
  __bf16* Wb   = (__bf16*)(ws + 4*MB);       // 6 MB (dead after gemm1)
  __bf16* Wob  = (__bf16*)(ws + 10*MB);      // 2 MB
  float*  P    = (float*) (ws + 12*MB);      // 24 MB  [q|k|v|og]
  float*  icap = (float*) (ws + 36*MB);
  float*  flog = (float*) (ws + 36*MB + 64*1024);
  float*  g_g  = (float*) (ws + 36*MB + 128*1024);
  float*  a_g  = (float*) (ws + 36*MB + 192*1024);
  float*  m_g  = (float*) (ws + 36*MB + 256*1024);
  float*  m0g  = (float*) (ws + 36*MB + 320*1024);
  float*  Ung  = (float*) (ws + 36*MB + 384*1024);
  float*  n0g  = (float*) (ws + 36*MB + 448*1024);
  float*  Ug   = (float*) (ws + 0);          // 8 MB, reuses xb+Wb[0:4MB] region
  float*  C0g  = (float*) (ws + 37*MB);      // 8 MB
  __bf16* houtb= (__bf16*)(ws + 45*MB);      // 4 MB

  cvt_f32_bf16<<<(2048*1024/4 + 255)/256, 256, 0, stream>>>(x, xb, 2048*1024/4);
  cvt_f32_bf16<<<(512*1024/4 + 255)/256, 256, 0, stream>>>(Wq, Wb + 0,          512*1024/4);
  cvt_f32_bf16<<<(512*1024/4 + 255)/256, 256, 0, stream>>>(Wk, Wb + 512*1024,   512*1024/4);
  cvt_f32_bf16<<<(1024*1024/4 + 255)/256, 256, 0, stream>>>(Wv, Wb + 1024*1024, 1024*1024/4);
  cvt_f32_bf16<<<(1024*1024/4 + 255)/256, 256, 0, stream>>>(Wog, Wb + 2048*1024, 1024*1024/4);
  cvt_f32_bf16<<<(1024*1024/4 + 255)/256, 256, 0, stream>>>(Wout, Wob, 1024*1024/4);

  gemm_bt<<<dim3(3072/128, 2048/128), 256, 0, stream>>>(xb, Wb, P, 2048, 3072, 1024);

  ifgate_kernel<<<2048, 256, 0, stream>>>(x, Wi, bi, Wf, bf_, icap, flog);
  gates_kernel<<<16, 64, 0, stream>>>(icap, flog, g_g, a_g, m_g, m0g);
  u_kernel<<<256, 256, 0, stream>>>(P, g_g, a_g, Ug, Ung);
  statescan_kernel<<<256, 512, 0, stream>>>(Ug, Ung, m0g, a_g, C0g, n0g);
  intra_kernel<<<256, 256, 0, stream>>>(P, g_g, a_g, m_g, m0g, C0g, n0g, gamma, houtb);

  gemm_bt<<<dim3(1024/128, 2048/128), 256, 0, stream>>>(houtb, Wob, y, 2048, 1024, 1024);
}

// Round 3
// 177.545 us; speedup vs baseline: 7.3459x; 1.2299x over previous
//
#include <hip/hip_runtime.h>
#include <hip/hip_bf16.h>
#include <math.h>

typedef __bf16 bf16x8 __attribute__((ext_vector_type(8)));
typedef float f32x4 __attribute__((ext_vector_type(4)));

#define NB 2
#define NS 1024
#define ND 1024
#define NH 8
#define NQK 512
#define NV 1024
#define DQK 64
#define DHV 128
#define CHUNK 64
#define NCHUNK 16

#define GLDS16(g, l) __builtin_amdgcn_global_load_lds((const __attribute__((address_space(1))) void*)(g), (__attribute__((address_space(3))) void*)(l), 16, 0, 0)

static __device__ __forceinline__ void split_bf16(float v, __bf16& hi, __bf16& lo) {
  hi = (__bf16)v;
  lo = (__bf16)(v - (float)hi);
}

// ---------------- fused f32 -> bf16 conversion (all 6 tensors, 1 launch) ----------------
__global__ __launch_bounds__(256) void cvt_all(const float* __restrict__ x,
    const float* __restrict__ wq, const float* __restrict__ wk,
    const float* __restrict__ wv, const float* __restrict__ wog,
    const float* __restrict__ wout,
    __bf16* __restrict__ xb, __bf16* __restrict__ wb, __bf16* __restrict__ wob) {
  long i = (long)blockIdx.x * 256 + threadIdx.x;   // float4 index
  const float* src; __bf16* dst;
  if (i < 524288)        { src = x    + i*4;                    dst = xb  + i*4; }
  else if (i < 655360)   { long j = i -  524288; src = wq  + j*4; dst = wb + j*4; }
  else if (i < 786432)   { long j = i -  655360; src = wk  + j*4; dst = wb +  524288 + j*4; }
  else if (i < 1048576)  { long j = i -  786432; src = wv  + j*4; dst = wb + 1048576 + j*4; }
  else if (i < 1310720)  { long j = i - 1048576; src = wog + j*4; dst = wb + 2097152 + j*4; }
  else                   { long j = i - 1310720; src = wout+ j*4; dst = wob + j*4; }
  float4 v = *(const float4*)src;
  __bf16 o[4];
  o[0] = (__bf16)v.x; o[1] = (__bf16)v.y; o[2] = (__bf16)v.z; o[3] = (__bf16)v.w;
  *(short4*)dst = *(const short4*)o;
}

// ---------------- bf16 GEMM, C[M,N] = A[M,K]*B[N,K]^T, f32 out ----------------
// 128x128 tile, 4 waves, BK=64, linear LDS + XOR-swizzle via pre-swizzled global src,
// global_load_lds width=16 (m97 recipe).
__global__ __launch_bounds__(256) void gemm_bt(const __bf16* __restrict__ A,
                                               const __bf16* __restrict__ Bm,
                                               float* __restrict__ C,
                                               int M, int N, int K) {
  __shared__ __bf16 smA[128 * 64];
  __shared__ __bf16 smB[128 * 64];
  const int tid = threadIdx.x;
  const int m0 = blockIdx.y * 128;
  const int n0 = blockIdx.x * 128;
  const int wid = tid >> 6, lane = tid & 63;
  const int wm = (wid >> 1) * 64, wn = (wid & 1) * 64;
  const int fr = lane & 15;
  const int g  = lane >> 4;
  f32x4 acc[4][4] = {};
  for (int kt = 0; kt < K; kt += 64) {
    // stage: 1024 slots (16B) per matrix; slot s -> row = s>>3, phys k16 = s&7,
    // logical k16 = (s&7) ^ (row&7). LDS stays linear; global src pre-swizzled.
    #pragma unroll
    for (int i = 0; i < 4; ++i) {
      const int sbase = i * 256 + wid * 64;
      const int s = sbase + lane;
      const int row = s >> 3;
      const int klog = (s & 7) ^ (row & 7);
      GLDS16(A  + (size_t)(m0 + row) * K + kt + klog * 8, smA + sbase * 8);
      GLDS16(Bm + (size_t)(n0 + row) * K + kt + klog * 8, smB + sbase * 8);
    }
    __syncthreads();
    #pragma unroll
    for (int kk = 0; kk < 2; ++kk) {
      const int kg = kk * 4 + g;
      bf16x8 af[4], bfv[4];
      #pragma unroll
      for (int f = 0; f < 4; ++f) {
        const int Ra = wm + f * 16 + fr;
        const int Rb = wn + f * 16 + fr;
        af[f]  = *(const bf16x8*)&smA[Ra * 64 + ((kg ^ (Ra & 7)) * 8)];
        bfv[f] = *(const bf16x8*)&smB[Rb * 64 + ((kg ^ (Rb & 7)) * 8)];
      }
      #pragma unroll
      for (int i = 0; i < 4; ++i)
        #pragma unroll
        for (int j = 0; j < 4; ++j)
          acc[i][j] = __builtin_amdgcn_mfma_f32_16x16x32_bf16(af[i], bfv[j], acc[i][j], 0, 0, 0);
    }
    __syncthreads();
  }
  const int orow = m0 + wm + g * 4;
  const int ocol = n0 + wn + fr;
  #pragma unroll
  for (int i = 0; i < 4; ++i)
    #pragma unroll
    for (int j = 0; j < 4; ++j)
      #pragma unroll
      for (int r = 0; r < 4; ++r)
        C[(size_t)(orow + i*16 + r) * N + (ocol + j*16)] = acc[i][j][r];
}

// ---------------- i/f gate pre-activations (full f32) ----------------
__global__ __launch_bounds__(256) void ifgate_kernel(const float* __restrict__ x,
    const float* __restrict__ Wi, const float* __restrict__ bi,
    const float* __restrict__ Wf, const float* __restrict__ bf_,
    float* __restrict__ icap, float* __restrict__ flog) {
  const int row = blockIdx.x;
  const int w = threadIdx.x >> 6;
  const int l = threadIdx.x & 63;
  const float* xr = x + (size_t)row * ND;
  float xv[16];
  #pragma unroll
  for (int t = 0; t < 16; ++t) xv[t] = xr[l + 64*t];
  for (int hh = 0; hh < 2; ++hh) {
    int h = w*2 + hh;
    const float* wi = Wi + (size_t)h * ND;
    const float* wf = Wf + (size_t)h * ND;
    float si = 0.f, sf = 0.f;
    #pragma unroll
    for (int t = 0; t < 16; ++t) {
      si += xv[t] * wi[l + 64*t];
      sf += xv[t] * wf[l + 64*t];
    }
    #pragma unroll
    for (int off = 32; off; off >>= 1) {
      si += __shfl_xor(si, off, 64);
      sf += __shfl_xor(sf, off, 64);
    }
    if (l == 0) {
      float ic = 15.f * tanhf((si + bi[h]) * (1.f/15.f));
      float fc = 15.f * tanhf((sf + bf_[h]) * (1.f/15.f));
      float fl = (fc >= 0.f) ? -log1pf(__expf(-fc)) : (fc - log1pf(__expf(fc)));
      icap[row*NH + h] = ic;
      flog[row*NH + h] = fl;
    }
  }
}

// ---------------- gate scan: per (b,h), chunked cumsum/cummax ----------------
__global__ __launch_bounds__(64) void gates_kernel(const float* __restrict__ icap,
    const float* __restrict__ flog, float* __restrict__ g_g, float* __restrict__ a_g,
    float* __restrict__ m_g, float* __restrict__ m0g) {
  const int bh = blockIdx.x;
  const int b = bh >> 3, h = bh & 7;
  const int l = threadIdx.x;
  float m0 = 0.f;
  for (int c = 0; c < NCHUNK; ++c) {
    const int t = c*CHUNK + l;
    const int row = b*NS + t;
    float B = flog[row*NH + h];
    float iv = icap[row*NH + h];
    #pragma unroll
    for (int d = 1; d < 64; d <<= 1) {
      float o = __shfl_up(B, d, 64);
      if (l >= d) B += o;
    }
    float g = iv - B;
    float cm = g;
    #pragma unroll
    for (int d = 1; d < 64; d <<= 1) {
      float o = __shfl_up(cm, d, 64);
      if (l >= d) cm = fmaxf(cm, o);
    }
    float a = fmaxf(m0, cm);
    float m = B + a;
    const int idx = bh*NS + t;
    g_g[idx] = g; a_g[idx] = a; m_g[idx] = m;
    if (l == 0) m0g[bh*NCHUNK + c] = m0;
    m0 = __shfl(m, 63, 64);
  }
}

// ---------------- per-chunk U = K^T diag(w) V (MFMA), u_n = K^T w (f32) ----------------
__global__ __launch_bounds__(256) void u_kernel(const float* __restrict__ P,
    const float* __restrict__ g_g, const float* __restrict__ a_g,
    float* __restrict__ Ug, float* __restrict__ Ung) {
  __shared__ float w_l[64];
  __shared__ float knP[4][64];
  __shared__ __bf16 ksT[64][72];    // [d][s]
  __shared__ __bf16 vwT[128][72];   // [u][s], w folded
  const int task = blockIdx.x;
  const int bh = task >> 4, c = task & 15;
  const int b = bh >> 3, h = bh & 7;
  const int t = threadIdx.x;
  const int row0 = b*NS + c*CHUNK;
  if (t < 64) {
    const float aL = a_g[bh*NS + c*CHUNK + 63];
    w_l[t] = __expf(g_g[bh*NS + c*CHUNK + t] - aL);
  }
  __syncthreads();
  // stage ksT (transposed K) + kn partial
  {
    const int d = t & 63, sh = t >> 6;        // s-chunk sh*16..+15
    const float* src = P + (size_t)(row0 + sh*16)*3072 + NQK + h*DQK + d;
    float kn = 0.f;
    __bf16 tmp[16];
    #pragma unroll
    for (int i = 0; i < 16; ++i) {
      float kv = src[(size_t)i * 3072];
      kn += kv * w_l[sh*16 + i];
      tmp[i] = (__bf16)kv;
    }
    *(float4*)&ksT[d][sh*16]     = *(const float4*)&tmp[0];
    *(float4*)&ksT[d][sh*16 + 8] = *(const float4*)&tmp[8];
    knP[sh][d] = kn;
  }
  // stage vwT (transposed V, * w)
  {
    const int u = t & 127, sh2 = t >> 7;      // s-chunk sh2*32..+31
    const float* src = P + (size_t)(row0 + sh2*32)*3072 + 2*NQK + h*DHV + u;
    #pragma unroll
    for (int q4 = 0; q4 < 4; ++q4) {
      __bf16 tmp[8];
      #pragma unroll
      for (int i = 0; i < 8; ++i) {
        int s = sh2*32 + q4*8 + i;
        tmp[i] = (__bf16)(src[(size_t)(q4*8 + i) * 3072] * w_l[s]);
      }
      *(float4*)&vwT[u][sh2*32 + q4*8] = *(const float4*)&tmp[0];
    }
  }
  __syncthreads();
  if (t < 64) Ung[task*64 + t] = knP[0][t] + knP[1][t] + knP[2][t] + knP[3][t];
  // MFMA: D[d][u] = sum_s ksT[d][s] * vwT[u][s]
  const int wid = t >> 6, lane = t & 63;
  const int fr = lane & 15, g = lane >> 4;
  f32x4 acc[8] = {};
  #pragma unroll
  for (int kk = 0; kk < 2; ++kk) {
    const int kg = kk*4 + g;
    bf16x8 af = *(const bf16x8*)&ksT[wid*16 + fr][kg*8];
    #pragma unroll
    for (int nt = 0; nt < 8; ++nt) {
      bf16x8 bv = *(const bf16x8*)&vwT[nt*16 + fr][kg*8];
      acc[nt] = __builtin_amdgcn_mfma_f32_16x16x32_bf16(af, bv, acc[nt], 0, 0, 0);
    }
  }
  float* ub = Ug + (size_t)task * 64 * 128;
  #pragma unroll
  for (int nt = 0; nt < 8; ++nt)
    #pragma unroll
    for (int r = 0; r < 4; ++r)
      ub[(size_t)(wid*16 + g*4 + r) * 128 + nt*16 + fr] = acc[nt][r];
}

// ---------------- inter-chunk state prefix scan (elementwise, 16 steps) ----------------
__global__ __launch_bounds__(512) void statescan_kernel(const float* __restrict__ Ug,
    const float* __restrict__ Ung, const float* __restrict__ m0g,
    const float* __restrict__ a_g, float* __restrict__ C0g, float* __restrict__ n0g) {
  const int bx = blockIdx.x;
  const int bh = bx >> 4, part = bx & 15;
  const int e = part*512 + threadIdx.x;
  float scale[NCHUNK];
  #pragma unroll
  for (int c = 0; c < NCHUNK; ++c)
    scale[c] = __expf(m0g[bh*NCHUNK + c] - a_g[bh*NS + c*CHUNK + 63]);
  float val = 0.f;
  for (int c = 0; c < NCHUNK; ++c) {
    size_t idx = ((size_t)(bh*NCHUNK + c))*8192 + e;
    C0g[idx] = val;
    val = scale[c]*val + Ug[idx];
  }
  if (part == 0 && threadIdx.x < 64) {
    float nv = 0.f;
    for (int c = 0; c < NCHUNK; ++c) {
      int idx = (bh*NCHUNK + c)*64 + threadIdx.x;
      n0g[idx] = nv;
      nv = scale[c]*nv + Ung[idx];
    }
  }
}

// ---------------- intra-chunk attention + inter + denom + LN + gate (MFMA) ----------------
// grid 512 = (task, jhalf); block 256 = 4 waves; wave (jt_local = wid>>1, half = wid&1).
__global__ __launch_bounds__(256) void intra_kernel(const float* __restrict__ P,
    const float* __restrict__ g_g, const float* __restrict__ a_g,
    const float* __restrict__ m_g, const float* __restrict__ m0g,
    const float* __restrict__ C0g, const float* __restrict__ n0g,
    const float* __restrict__ gamma, __bf16* __restrict__ hout) {
  __shared__ __bf16 q_hi[32][72], q_lo[32][72];
  __shared__ __bf16 kvreg[2*64*72];           // phase A: k_hi | k_lo ; phase B: vsT[128][72]
  __shared__ __bf16 c0T[128][72];             // [u][d]
  __shared__ __bf16 Ps[32][72];               // [j][s] bf16 weights
  __shared__ float g_l[64], n0_l[64], a_l[32], m_l[32], cI_l[32];
  __shared__ float qnA[2][32], qnI_l[32], lnS[2][32], lnQ[2][32];

  const int blk = blockIdx.x;
  const int task = blk >> 1, jhalf = blk & 1;
  const int bh = task >> 4, c = task & 15;
  const int b = bh >> 3, h = bh & 7;
  const int t = threadIdx.x;
  const int wid = t >> 6, lane = t & 63;
  const int fr = lane & 15, lg = lane >> 4;
  const int jt_local = wid >> 1, half = wid & 1;
  const int jtg = jhalf*2 + jt_local;
  const int row0 = b*NS + c*CHUNK;
  const int jrow0 = row0 + jhalf*32;
  __bf16* k_hi = kvreg;
  __bf16* k_lo = kvreg + 64*72;

  // ---- stage q (32 rows, scaled 0.125, hi/lo)
  {
    const int r = t >> 3, c8 = (t & 7) * 8;
    const float* src = P + (size_t)(jrow0 + r)*3072 + h*DQK + c8;
    float4 v0 = *(const float4*)src;
    float4 v1 = *(const float4*)(src + 4);
    float vv[8] = {v0.x,v0.y,v0.z,v0.w,v1.x,v1.y,v1.z,v1.w};
    __bf16 hi8[8], lo8[8];
    #pragma unroll
    for (int i = 0; i < 8; ++i) split_bf16(vv[i]*0.125f, hi8[i], lo8[i]);
    *(float4*)&q_hi[r][c8] = *(const float4*)hi8;
    *(float4*)&q_lo[r][c8] = *(const float4*)lo8;
  }
  // ---- stage k (64 rows, hi/lo)
  {
    const int r = t >> 2, c16 = (t & 3) * 16;
    const float* src = P + (size_t)(row0 + r)*3072 + NQK + h*DQK + c16;
    __bf16 hi8[16], lo8[16];
    #pragma unroll
    for (int i = 0; i < 16; ++i) split_bf16(src[i], hi8[i], lo8[i]);
    *(float4*)&k_hi[r*72 + c16]     = *(const float4*)&hi8[0];
    *(float4*)&k_hi[r*72 + c16 + 8] = *(const float4*)&hi8[8];
    *(float4*)&k_lo[r*72 + c16]     = *(const float4*)&lo8[0];
    *(float4*)&k_lo[r*72 + c16 + 8] = *(const float4*)&lo8[8];
  }
  // ---- stage c0T (transposed C0: [u][d])
  {
    const int u = t & 127, dh = t >> 7;
    const float* src = C0g + (size_t)task*8192 + (size_t)(dh*32)*128 + u;
    #pragma unroll
    for (int q4 = 0; q4 < 4; ++q4) {
      __bf16 tmp[8];
      #pragma unroll
      for (int i = 0; i < 8; ++i) tmp[i] = (__bf16)src[(size_t)(q4*8 + i) * 128];
      *(float4*)&c0T[u][dh*32 + q4*8] = *(const float4*)tmp;
    }
  }
  // ---- gates / n0 / misc
  const float m0v = m0g[bh*NCHUNK + c];
  if (t < 64) {
    g_l[t]  = g_g[bh*NS + c*CHUNK + t];
    n0_l[t] = n0g[task*64 + t];
  } else if (t < 96) {
    int jl = t - 64;
    float av = a_g[bh*NS + c*CHUNK + jhalf*32 + jl];
    a_l[jl] = av;
    m_l[jl] = m_g[bh*NS + c*CHUNK + jhalf*32 + jl];
    cI_l[jl] = __expf(m0v - av);
  }
  __syncthreads();

  // ---- Phase A: QK^T (hi/lo, ~f32), mask+exp, row sums, P->bf16
  float rsum[4] = {0.f, 0.f, 0.f, 0.f};
  for (int st = half; st < 4; st += 2) {
    if (st <= jtg) {
      f32x4 sacc = {};
      #pragma unroll
      for (int kk = 0; kk < 2; ++kk) {
        const int kg = kk*4 + lg;
        bf16x8 qh = *(const bf16x8*)&q_hi[jt_local*16 + fr][kg*8];
        bf16x8 ql = *(const bf16x8*)&q_lo[jt_local*16 + fr][kg*8];
        bf16x8 kh = *(const bf16x8*)&k_hi[(st*16 + fr)*72 + kg*8];
        bf16x8 kl = *(const bf16x8*)&k_lo[(st*16 + fr)*72 + kg*8];
        sacc = __builtin_amdgcn_mfma_f32_16x16x32_bf16(qh, kh, sacc, 0, 0, 0);
        sacc = __builtin_amdgcn_mfma_f32_16x16x32_bf16(qh, kl, sacc, 0, 0, 0);
        sacc = __builtin_amdgcn_mfma_f32_16x16x32_bf16(ql, kh, sacc, 0, 0, 0);
      }
      const int s_c = st*16 + fr;
      const float gs = g_l[s_c];
      #pragma unroll
      for (int r = 0; r < 4; ++r) {
        const int jl = jt_local*16 + lg*4 + r;
        const int j_c = jhalf*32 + jl;
        float w = (s_c <= j_c) ? __expf(gs - a_l[jl]) : 0.f;
        float p = sacc[r] * w;
        rsum[r] += p;
        Ps[jl][s_c] = (__bf16)p;
      }
    } else {
      #pragma unroll
      for (int r = 0; r < 4; ++r)
        Ps[jt_local*16 + lg*4 + r][st*16 + fr] = (__bf16)0.f;
    }
  }
  #pragma unroll
  for (int r = 0; r < 4; ++r) {
    #pragma unroll
    for (int off = 1; off < 16; off <<= 1) rsum[r] += __shfl_xor(rsum[r], off, 64);
  }
  if (fr == 0) {
    #pragma unroll
    for (int r = 0; r < 4; ++r) qnA[half][jt_local*16 + lg*4 + r] = rsum[r];
  }

  // ---- inter term: acc[j][u] = q_hi . c0T, then * cI[j]
  f32x4 acc[4] = {};
  #pragma unroll
  for (int kk = 0; kk < 2; ++kk) {
    const int kg = kk*4 + lg;
    bf16x8 aq = *(const bf16x8*)&q_hi[jt_local*16 + fr][kg*8];
    #pragma unroll
    for (int nt = 0; nt < 4; ++nt) {
      bf16x8 bc = *(const bf16x8*)&c0T[(half*4 + nt)*16 + fr][kg*8];
      acc[nt] = __builtin_amdgcn_mfma_f32_16x16x32_bf16(aq, bc, acc[nt], 0, 0, 0);
    }
  }
  {
    float ci4[4];
    #pragma unroll
    for (int r = 0; r < 4; ++r) ci4[r] = cI_l[jt_local*16 + lg*4 + r];
    #pragma unroll
    for (int nt = 0; nt < 4; ++nt)
      #pragma unroll
      for (int r = 0; r < 4; ++r) acc[nt][r] *= ci4[r];
  }
  // ---- qn_inter (half==1 waves): cI[j] * sum_d q[j][d]*n0[d]
  if (half == 1) {
    const int jl = jt_local*16 + fr;
    const int d0 = lg*16;
    float s = 0.f;
    #pragma unroll
    for (int i = 0; i < 16; ++i) {
      float qv = (float)q_hi[jl][d0+i] + (float)q_lo[jl][d0+i];
      s += qv * n0_l[d0+i];
    }
    s += __shfl_xor(s, 16, 64);
    s += __shfl_xor(s, 32, 64);
    if (lane < 16) qnI_l[jl] = cI_l[jl] * s;
  }
  __syncthreads();

  // ---- Phase B: stage vsT (transposed V) over k region
  {
    __bf16* vsT = kvreg;
    const int u = t & 127, sh = t >> 7;
    const float* src = P + (size_t)(row0 + sh*32)*3072 + 2*NQK + h*DHV + u;
    #pragma unroll
    for (int q4 = 0; q4 < 4; ++q4) {
      __bf16 tmp[8];
      #pragma unroll
      for (int i = 0; i < 8; ++i) tmp[i] = (__bf16)src[(size_t)(q4*8 + i) * 3072];
      *(float4*)&kvreg[u*72 + sh*32 + q4*8] = *(const float4*)tmp;
    }
  }
  __syncthreads();

  // ---- PV: acc += Ps . vsT
  #pragma unroll
  for (int kk = 0; kk < 2; ++kk) {
    const int kg = kk*4 + lg;
    bf16x8 ap = *(const bf16x8*)&Ps[jt_local*16 + fr][kg*8];
    #pragma unroll
    for (int nt = 0; nt < 4; ++nt) {
      bf16x8 bv = *(const bf16x8*)&kvreg[((half*4 + nt)*16 + fr)*72 + kg*8];
      acc[nt] = __builtin_amdgcn_mfma_f32_16x16x32_bf16(ap, bv, acc[nt], 0, 0, 0);
    }
  }

  // ---- epilogue part 1: denom, LN partials over this wave's 64 u
  #pragma unroll
  for (int r = 0; r < 4; ++r) {
    const int jl = jt_local*16 + lg*4 + r;
    float qn = qnA[0][jl] + qnA[1][jl] + qnI_l[jl];
    float denom = fmaxf(fabsf(qn), __expf(-m_l[jl])) + 1e-6f;
    float rd = 1.f / denom;
    float s = 0.f, q2 = 0.f;
    #pragma unroll
    for (int nt = 0; nt < 4; ++nt) {
      float hv = acc[nt][r] * rd;
      acc[nt][r] = hv;
      s += hv; q2 += hv*hv;
    }
    #pragma unroll
    for (int off = 1; off < 16; off <<= 1) {
      s  += __shfl_xor(s,  off, 64);
      q2 += __shfl_xor(q2, off, 64);
    }
    if (fr == 0) { lnS[half][jl] = s; lnQ[half][jl] = q2; }
  }
  __syncthreads();

  // ---- epilogue part 2: LN + output gate + bf16 store
  #pragma unroll
  for (int r = 0; r < 4; ++r) {
    const int jl = jt_local*16 + lg*4 + r;
    float sm = lnS[0][jl] + lnS[1][jl];
    float sq = lnQ[0][jl] + lnQ[1][jl];
    float mu = sm * (1.f/128.f);
    float var = sq * (1.f/128.f) - mu*mu;
    float rstd = rsqrtf(var + 1e-6f);
    const int rowg = jrow0 + jl;
    #pragma unroll
    for (int nt = 0; nt < 4; ++nt) {
      const int u = (half*4 + nt)*16 + fr;
      float og = P[(size_t)rowg*3072 + 2048 + h*DHV + u];
      float sg = 1.f / (1.f + __expf(-og));
      float hn = (acc[nt][r] - mu) * rstd * gamma[h*DHV + u] * sg;
      hout[(size_t)rowg*NV + h*DHV + u] = (__bf16)hn;
    }
  }
}

extern "C" void kernel_launch(void* const* d_in, const int* in_sizes, int n_in,
                              void* d_out, int out_size, void* d_ws, size_t ws_size,
                              hipStream_t stream) {
  const float* x    = (const float*)d_in[0];
  const float* Wq   = (const float*)d_in[1];
  const float* Wk   = (const float*)d_in[2];
  const float* Wv   = (const float*)d_in[3];
  const float* Wog  = (const float*)d_in[4];
  const float* Wi   = (const float*)d_in[5];
  const float* bi   = (const float*)d_in[6];
  const float* Wf   = (const float*)d_in[7];
  const float* bf_  = (const float*)d_in[8];
  const float* gamma= (const float*)d_in[9];
  const float* Wout = (const float*)d_in[10];
  float* y = (float*)d_out;

  char* ws = (char*)d_ws;
  const size_t MB = 1u << 20;
  __bf16* xb   = (__bf16*)(ws + 0);          // 4 MB (dead after gemm1)
  __bf16* Wb   = (__bf16*)(ws + 4*MB);       // 6 MB (dead after gemm1)
  __bf16* Wob  = (__bf16*)(ws + 10*MB);      // 2 MB
  float*  P    = (float*) (ws + 12*MB);      // 24 MB  [q|k|v|og]
  float*  icap = (float*) (ws + 36*MB);
  float*  flog = (float*) (ws + 36*MB + 64*1024);
  float*  g_g  = (float*) (ws + 36*MB + 128*1024);
  float*  a_g  = (float*) (ws + 36*MB + 192*1024);
  float*  m_g  = (float*) (ws + 36*MB + 256*1024);
  float*  m0g  = (float*) (ws + 36*MB + 320*1024);
  float*  Ung  = (float*) (ws + 36*MB + 384*1024);
  float*  n0g  = (float*) (ws + 36*MB + 448*1024);
  float*  Ug   = (float*) (ws + 0);          // 8 MB, reuses xb+Wb region
  float*  C0g  = (float*) (ws + 37*MB);      // 8 MB
  __bf16* houtb= (__bf16*)(ws + 45*MB);      // 4 MB

  cvt_all<<<6144, 256, 0, stream>>>(x, Wq, Wk, Wv, Wog, Wout, xb, Wb, Wob);

  gemm_bt<<<dim3(3072/128, 2048/128), 256, 0, stream>>>(xb, Wb, P, 2048, 3072, 1024);

  ifgate_kernel<<<2048, 256, 0, stream>>>(x, Wi, bi, Wf, bf_, icap, flog);
  gates_kernel<<<16, 64, 0, stream>>>(icap, flog, g_g, a_g, m_g, m0g);
  u_kernel<<<256, 256, 0, stream>>>(P, g_g, a_g, Ug, Ung);
  statescan_kernel<<<256, 512, 0, stream>>>(Ug, Ung, m0g, a_g, C0g, n0g);
  intra_kernel<<<512, 256, 0, stream>>>(P, g_g, a_g, m_g, m0g, C0g, n0g, gamma, houtb);

  gemm_bt<<<dim3(1024/128, 2048/128), 256, 0, stream>>>(houtb, Wob, y, 2048, 1024, 1024);
}

// Round 4
// 176.372 us; speedup vs baseline: 7.3948x; 1.0067x over previous
//
#include <hip/hip_runtime.h>
#include <hip/hip_bf16.h>
#include <math.h>

typedef __bf16 bf16x8 __attribute__((ext_vector_type(8)));
typedef float f32x4 __attribute__((ext_vector_type(4)));

#define NB 2
#define NS 1024
#define ND 1024
#define NH 8
#define NQK 512
#define NV 1024
#define DQK 64
#define DHV 128
#define CHUNK 64
#define NCHUNK 16

#define GLDS16(g, l) __builtin_amdgcn_global_load_lds((const __attribute__((address_space(1))) void*)(g), (__attribute__((address_space(3))) void*)(l), 16, 0, 0)

static __device__ __forceinline__ void split_bf16(float v, __bf16& hi, __bf16& lo) {
  hi = (__bf16)v;
  lo = (__bf16)(v - (float)hi);
}

// bijective XCD swizzle (m204); requires nothing of nwg
static __device__ __forceinline__ int xcd_swz(int orig, int nwg) {
  int q = nwg >> 3, r = nwg & 7;
  int xcd = orig & 7, idx = orig >> 3;
  int base = (xcd < r) ? xcd * (q + 1) : r * (q + 1) + (xcd - r) * q;
  return base + idx;
}

// ---------------- fused f32 -> bf16 conversion (all 6 tensors, 1 launch) ----------------
__global__ __launch_bounds__(256) void cvt_all(const float* __restrict__ x,
    const float* __restrict__ wq, const float* __restrict__ wk,
    const float* __restrict__ wv, const float* __restrict__ wog,
    const float* __restrict__ wout,
    __bf16* __restrict__ xb, __bf16* __restrict__ wb, __bf16* __restrict__ wob) {
  long i = (long)blockIdx.x * 256 + threadIdx.x;   // float4 index
  const float* src; __bf16* dst;
  if (i < 524288)        { src = x    + i*4;                    dst = xb  + i*4; }
  else if (i < 655360)   { long j = i -  524288; src = wq  + j*4; dst = wb + j*4; }
  else if (i < 786432)   { long j = i -  655360; src = wk  + j*4; dst = wb +  524288 + j*4; }
  else if (i < 1048576)  { long j = i -  786432; src = wv  + j*4; dst = wb + 1048576 + j*4; }
  else if (i < 1310720)  { long j = i - 1048576; src = wog + j*4; dst = wb + 2097152 + j*4; }
  else                   { long j = i - 1310720; src = wout+ j*4; dst = wob + j*4; }
  float4 v = *(const float4*)src;
  __bf16 o[4];
  o[0] = (__bf16)v.x; o[1] = (__bf16)v.y; o[2] = (__bf16)v.z; o[3] = (__bf16)v.w;
  *(short4*)dst = *(const short4*)o;
}

// ---------------- staging macro shared by both GEMMs ----------------
#define GEMM_STAGE(Abuf, Bbuf, Aptr, Bptr, Krun, ktv)                         \
  do {                                                                        \
    _Pragma("unroll")                                                         \
    for (int i_ = 0; i_ < 4; ++i_) {                                          \
      const int sb_ = i_ * 256 + wid * 64;                                    \
      const int s_ = sb_ + lane;                                              \
      const int row_ = s_ >> 3;                                               \
      const int klog_ = (s_ & 7) ^ (row_ & 7);                                \
      GLDS16(Aptr + (size_t)(m0 + row_) * Krun + (ktv) * 64 + klog_ * 8, Abuf + sb_ * 8); \
      GLDS16(Bptr + (size_t)(n0 + row_) * Krun + (ktv) * 64 + klog_ * 8, Bbuf + sb_ * 8); \
    }                                                                         \
  } while (0)

// ---------------- generic bf16 GEMM, C[M,N] = A[M,K]*B[N,K]^T, f32 out ----------------
// 128x128 tile, dbuf prefetch (T3-min), source-swizzled LDS, XCD swizzle.
__global__ __launch_bounds__(256) void gemm_bt(const __bf16* __restrict__ A,
                                               const __bf16* __restrict__ Bm,
                                               float* __restrict__ C,
                                               int M, int N, int K, int ntn, int nwg) {
  __shared__ __bf16 smA[2][128 * 64];
  __shared__ __bf16 smB[2][128 * 64];
  const int wg = xcd_swz(blockIdx.x, nwg);
  const int m0 = (wg / ntn) * 128;
  const int n0 = (wg % ntn) * 128;
  const int tid = threadIdx.x;
  const int wid = tid >> 6, lane = tid & 63;
  const int wm = (wid >> 1) * 64, wn = (wid & 1) * 64;
  const int fr = lane & 15;
  const int g  = lane >> 4;
  f32x4 acc[4][4] = {};
  const int NT = K >> 6;
  GEMM_STAGE(smA[0], smB[0], A, Bm, K, 0);
  int cur = 0;
  for (int kt = 0; kt < NT; ++kt) {
    __syncthreads();                       // drains GLDS for buf[cur] + prior ds_reads
    if (kt + 1 < NT) GEMM_STAGE(smA[cur ^ 1], smB[cur ^ 1], A, Bm, K, kt + 1);
    #pragma unroll
    for (int kk = 0; kk < 2; ++kk) {
      const int kg = kk * 4 + g;
      bf16x8 af[4], bfv[4];
      #pragma unroll
      for (int f = 0; f < 4; ++f) {
        const int Ra = wm + f * 16 + fr;
        const int Rb = wn + f * 16 + fr;
        af[f]  = *(const bf16x8*)&smA[cur][Ra * 64 + ((kg ^ (Ra & 7)) * 8)];
        bfv[f] = *(const bf16x8*)&smB[cur][Rb * 64 + ((kg ^ (Rb & 7)) * 8)];
      }
      #pragma unroll
      for (int i = 0; i < 4; ++i)
        #pragma unroll
        for (int j = 0; j < 4; ++j)
          acc[i][j] = __builtin_amdgcn_mfma_f32_16x16x32_bf16(af[i], bfv[j], acc[i][j], 0, 0, 0);
    }
    cur ^= 1;
  }
  const int orow = m0 + wm + g * 4;
  const int ocol = n0 + wn + fr;
  #pragma unroll
  for (int i = 0; i < 4; ++i)
    #pragma unroll
    for (int j = 0; j < 4; ++j)
      #pragma unroll
      for (int r = 0; r < 4; ++r)
        C[(size_t)(orow + i*16 + r) * N + (ocol + j*16)] = acc[i][j][r];
}

// ---------------- projection GEMM with format-aware epilogue ----------------
// P[2048,3072] = xb * Wb^T ; cols 0-511 -> q (x0.125, hi/lo bf16, row-swizzled)
// 512-1023 -> k (hi/lo bf16 swz + kT tiles), 1024-2047 -> vT tiles, 2048-3071 -> sigmoid f16
__global__ __launch_bounds__(256) void gemm_proj(const __bf16* __restrict__ A,
    const __bf16* __restrict__ Bm,
    __bf16* __restrict__ qh, __bf16* __restrict__ ql,
    __bf16* __restrict__ kh, __bf16* __restrict__ kl,
    __bf16* __restrict__ kT, __bf16* __restrict__ vT,
    _Float16* __restrict__ ogs) {
  __shared__ __bf16 smA[2][128 * 64];
  __shared__ __bf16 smB[2][128 * 64];
  const int wg = xcd_swz(blockIdx.x, 384);
  const int m0 = (wg / 24) * 128;
  const int n0 = (wg % 24) * 128;
  const int tid = threadIdx.x;
  const int wid = tid >> 6, lane = tid & 63;
  const int wm = (wid >> 1) * 64, wn = (wid & 1) * 64;
  const int fr = lane & 15;
  const int g  = lane >> 4;
  f32x4 acc[4][4] = {};
  GEMM_STAGE(smA[0], smB[0], A, Bm, 1024, 0);
  int cur = 0;
  for (int kt = 0; kt < 16; ++kt) {
    __syncthreads();
    if (kt + 1 < 16) GEMM_STAGE(smA[cur ^ 1], smB[cur ^ 1], A, Bm, 1024, kt + 1);
    #pragma unroll
    for (int kk = 0; kk < 2; ++kk) {
      const int kg = kk * 4 + g;
      bf16x8 af[4], bfv[4];
      #pragma unroll
      for (int f = 0; f < 4; ++f) {
        const int Ra = wm + f * 16 + fr;
        const int Rb = wn + f * 16 + fr;
        af[f]  = *(const bf16x8*)&smA[cur][Ra * 64 + ((kg ^ (Ra & 7)) * 8)];
        bfv[f] = *(const bf16x8*)&smB[cur][Rb * 64 + ((kg ^ (Rb & 7)) * 8)];
      }
      #pragma unroll
      for (int i = 0; i < 4; ++i)
        #pragma unroll
        for (int j = 0; j < 4; ++j)
          acc[i][j] = __builtin_amdgcn_mfma_f32_16x16x32_bf16(af[i], bfv[j], acc[i][j], 0, 0, 0);
    }
    cur ^= 1;
  }
  const int orow = m0 + wm + g * 4;
  const int ocol = n0 + wn + fr;
  const int rng = n0 >> 9;   // 0: q, 1: k, 2..3: v, 4..5: og
  if (rng == 0 || rng == 1) {
    __bf16* Hb = (rng == 0) ? qh : kh;
    __bf16* Lb = (rng == 0) ? ql : kl;
    const float sc = (rng == 0) ? 0.125f : 1.0f;
    #pragma unroll
    for (int i = 0; i < 4; ++i)
      #pragma unroll
      for (int j = 0; j < 4; ++j) {
        const int col = (ocol + j*16) & 511;      // within tensor
        const int d = col & 63;
        const int hb = col & ~63;
        __bf16 t4[4];
        #pragma unroll
        for (int r = 0; r < 4; ++r) {
          const int row = orow + i*16 + r;
          float v = acc[i][j][r] * sc;
          __bf16 hi, lo; split_bf16(v, hi, lo);
          t4[r] = hi;
          const int off = row*512 + hb + ((((d>>3) ^ (row&7))) << 3) + (d & 7);
          Hb[off] = hi;
          Lb[off] = lo;
        }
        if (rng == 1) {
          const int row0r = orow + i*16;
          const int bh = ((row0r >> 10) << 3) + (col >> 6);
          const int c = (row0r >> 6) & 15;
          const int s0 = (row0r & 63);
          const int off = ((bh*16 + c)*64 + d)*64 + (((s0>>3) ^ (d&7)) << 3) + (s0 & 7);
          *(short4*)&kT[off] = *(const short4*)t4;
        }
      }
  } else if (rng == 2 || rng == 3) {
    #pragma unroll
    for (int i = 0; i < 4; ++i)
      #pragma unroll
      for (int j = 0; j < 4; ++j) {
        const int col = (ocol + j*16) & 1023;
        const int u = col & 127;
        __bf16 t4[4];
        #pragma unroll
        for (int r = 0; r < 4; ++r) t4[r] = (__bf16)acc[i][j][r];
        const int row0r = orow + i*16;
        const int bh = ((row0r >> 10) << 3) + (col >> 7);
        const int c = (row0r >> 6) & 15;
        const int s0 = (row0r & 63);
        const int off = ((bh*16 + c)*128 + u)*64 + (((s0>>3) ^ (u&7)) << 3) + (s0 & 7);
        *(short4*)&vT[off] = *(const short4*)t4;
      }
  } else {
    #pragma unroll
    for (int i = 0; i < 4; ++i)
      #pragma unroll
      for (int j = 0; j < 4; ++j) {
        const int col = (ocol + j*16) & 1023;
        #pragma unroll
        for (int r = 0; r < 4; ++r) {
          const int row = orow + i*16 + r;
          float sg = 1.f / (1.f + __expf(-acc[i][j][r]));
          ogs[(size_t)row*1024 + col] = (_Float16)sg;
        }
      }
  }
}

// ---------------- i/f gate pre-activations (full f32) ----------------
__global__ __launch_bounds__(256) void ifgate_kernel(const float* __restrict__ x,
    const float* __restrict__ Wi, const float* __restrict__ bi,
    const float* __restrict__ Wf, const float* __restrict__ bf_,
    float* __restrict__ icap, float* __restrict__ flog) {
  const int row = blockIdx.x;
  const int w = threadIdx.x >> 6;
  const int l = threadIdx.x & 63;
  const float* xr = x + (size_t)row * ND;
  float xv[16];
  #pragma unroll
  for (int t = 0; t < 16; ++t) xv[t] = xr[l + 64*t];
  for (int hh = 0; hh < 2; ++hh) {
    int h = w*2 + hh;
    const float* wi = Wi + (size_t)h * ND;
    const float* wf = Wf + (size_t)h * ND;
    float si = 0.f, sf = 0.f;
    #pragma unroll
    for (int t = 0; t < 16; ++t) {
      si += xv[t] * wi[l + 64*t];
      sf += xv[t] * wf[l + 64*t];
    }
    #pragma unroll
    for (int off = 32; off; off >>= 1) {
      si += __shfl_xor(si, off, 64);
      sf += __shfl_xor(sf, off, 64);
    }
    if (l == 0) {
      float ic = 15.f * tanhf((si + bi[h]) * (1.f/15.f));
      float fc = 15.f * tanhf((sf + bf_[h]) * (1.f/15.f));
      float fl = (fc >= 0.f) ? -log1pf(__expf(-fc)) : (fc - log1pf(__expf(fc)));
      icap[row*NH + h] = ic;
      flog[row*NH + h] = fl;
    }
  }
}

// ---------------- gate scan: per (b,h), chunked cumsum/cummax ----------------
__global__ __launch_bounds__(64) void gates_kernel(const float* __restrict__ icap,
    const float* __restrict__ flog, float* __restrict__ g_g, float* __restrict__ a_g,
    float* __restrict__ m_g, float* __restrict__ m0g) {
  const int bh = blockIdx.x;
  const int b = bh >> 3, h = bh & 7;
  const int l = threadIdx.x;
  float m0 = 0.f;
  for (int c = 0; c < NCHUNK; ++c) {
    const int t = c*CHUNK + l;
    const int row = b*NS + t;
    float B = flog[row*NH + h];
    float iv = icap[row*NH + h];
    #pragma unroll
    for (int d = 1; d < 64; d <<= 1) {
      float o = __shfl_up(B, d, 64);
      if (l >= d) B += o;
    }
    float g = iv - B;
    float cm = g;
    #pragma unroll
    for (int d = 1; d < 64; d <<= 1) {
      float o = __shfl_up(cm, d, 64);
      if (l >= d) cm = fmaxf(cm, o);
    }
    float a = fmaxf(m0, cm);
    float m = B + a;
    const int idx = bh*NS + t;
    g_g[idx] = g; a_g[idx] = a; m_g[idx] = m;
    if (l == 0) m0g[bh*NCHUNK + c] = m0;
    m0 = __shfl(m, 63, 64);
  }
}

// ---------------- per-chunk U^T[u][d] = sum_s v[s][u] (w_s k[s][d]) via MFMA ----------------
__global__ __launch_bounds__(256) void u_kernel(const __bf16* __restrict__ kT,
    const __bf16* __restrict__ vT, const float* __restrict__ g_g,
    const float* __restrict__ a_g, float* __restrict__ Ut, float* __restrict__ Ung) {
  __shared__ __bf16 kts[64 * 64];
  __shared__ __bf16 vts[128 * 64];
  __shared__ float w_l[64];
  const int task = blockIdx.x;
  const int bh = task >> 4, c = task & 15;
  const int t = threadIdx.x;
  const int wid = t >> 6, lane = t & 63;
  const int fr = lane & 15, g = lane >> 4;
  if (t < 64) {
    const float aL = a_g[bh*NS + c*CHUNK + 63];
    w_l[t] = __expf(g_g[bh*NS + c*CHUNK + t] - aL);
  }
  // linear GLDS of pre-swizzled tiles
  {
    const int sb = wid * 64;
    #pragma unroll
    for (int i = 0; i < 2; ++i) {
      const int s = i*256 + sb + lane;
      GLDS16(kT + (size_t)task*4096 + s*8, kts + (i*256 + sb)*8);
    }
    #pragma unroll
    for (int i = 0; i < 4; ++i) {
      const int s = i*256 + sb + lane;
      GLDS16(vT + (size_t)task*8192 + s*8, vts + (i*256 + sb)*8);
    }
  }
  __syncthreads();
  // wave wid: d-tile wid (rows wid*16..+15); 8 u-tiles
  f32x4 acc[8] = {};
  #pragma unroll
  for (int kk = 0; kk < 2; ++kk) {
    const int kg = kk*4 + g;
    const int Ra = wid*16 + fr;
    bf16x8 afr = *(const bf16x8*)&kts[Ra*64 + ((kg ^ (Ra & 7)) * 8)];
    bf16x8 afw;
    #pragma unroll
    for (int j = 0; j < 8; ++j) afw[j] = (__bf16)((float)afr[j] * w_l[kg*8 + j]);
    #pragma unroll
    for (int nt = 0; nt < 8; ++nt) {
      const int Rb = nt*16 + fr;
      bf16x8 bv = *(const bf16x8*)&vts[Rb*64 + ((kg ^ (Rb & 7)) * 8)];
      acc[nt] = __builtin_amdgcn_mfma_f32_16x16x32_bf16(afw, bv, acc[nt], 0, 0, 0);
    }
  }
  // D[d-row][u-col]: col=lane&15 -> u tile col, row = g*4+r -> d. Write Ut[u][d] f32.
  float* ub = Ut + (size_t)task * 8192;
  #pragma unroll
  for (int nt = 0; nt < 8; ++nt) {
    const int u = nt*16 + fr;
    *(f32x4*)&ub[u*64 + wid*16 + g*4] = acc[nt];
  }
  // Ung[d] = sum_s w_s k[s][d]
  if (t < 64) {
    float s = 0.f;
    #pragma unroll
    for (int blk = 0; blk < 8; ++blk) {
      bf16x8 kv = *(const bf16x8*)&kts[t*64 + ((blk ^ (t & 7)) * 8)];
      #pragma unroll
      for (int j = 0; j < 8; ++j) s += (float)kv[j] * w_l[blk*8 + j];
    }
    Ung[task*64 + t] = s;
  }
}

// ---------------- inter-chunk state prefix scan; emits swizzled bf16 C0T ----------------
__global__ __launch_bounds__(512) void statescan_kernel(const float* __restrict__ Ut,
    const float* __restrict__ Ung, const float* __restrict__ m0g,
    const float* __restrict__ a_g, __bf16* __restrict__ C0T, float* __restrict__ n0g) {
  const int bh = blockIdx.x >> 1, part = blockIdx.x & 1;
  const int e8 = part*512 + threadIdx.x;     // group of 8 d for one u
  const int u = e8 >> 3, d8 = e8 & 7;
  const int dsto = u*64 + ((d8 ^ (u & 7)) << 3);
  const int srco = u*64 + d8*8;
  float scale[NCHUNK];
  #pragma unroll
  for (int c = 0; c < NCHUNK; ++c)
    scale[c] = __expf(m0g[bh*NCHUNK + c] - a_g[bh*NS + c*CHUNK + 63]);
  float val[8] = {};
  for (int c = 0; c < NCHUNK; ++c) {
    const size_t base = ((size_t)(bh*NCHUNK + c)) * 8192;
    __bf16 o[8];
    #pragma unroll
    for (int j = 0; j < 8; ++j) o[j] = (__bf16)val[j];
    *(float4*)&C0T[base + dsto] = *(const float4*)o;
    f32x4 u0 = *(const f32x4*)&Ut[base + srco];
    f32x4 u1 = *(const f32x4*)&Ut[base + srco + 4];
    #pragma unroll
    for (int j = 0; j < 4; ++j) {
      val[j]   = scale[c]*val[j]   + u0[j];
      val[j+4] = scale[c]*val[j+4] + u1[j];
    }
  }
  if (part == 0 && threadIdx.x < 64) {
    float nv = 0.f;
    for (int c = 0; c < NCHUNK; ++c) {
      int idx = (bh*NCHUNK + c)*64 + threadIdx.x;
      n0g[idx] = nv;
      nv = scale[c]*nv + Ung[idx];
    }
  }
}

// ---------------- intra-chunk attention + inter + denom + LN + gate (MFMA, GLDS-staged) ----------------
__global__ __launch_bounds__(256) void intra_kernel(
    const __bf16* __restrict__ qh, const __bf16* __restrict__ ql,
    const __bf16* __restrict__ kh, const __bf16* __restrict__ kl,
    const __bf16* __restrict__ vT, const __bf16* __restrict__ C0T,
    const _Float16* __restrict__ ogs,
    const float* __restrict__ g_g, const float* __restrict__ a_g,
    const float* __restrict__ m_g, const float* __restrict__ m0g,
    const float* __restrict__ n0g,
    const float* __restrict__ gamma, __bf16* __restrict__ hout) {
  __shared__ __bf16 qh_s[32*64], ql_s[32*64];
  __shared__ __bf16 kh_s[64*64], kl_s[64*64];
  __shared__ __bf16 vt_s[128*64];
  __shared__ __bf16 c0_s[128*64];
  __shared__ __bf16 Ps[32*72];
  __shared__ float g_l[64], n0_l[64], a_l[32], m_l[32], cI_l[32];
  __shared__ float qnA[2][32], qnI_l[32], lnS[2][32], lnQ[2][32];

  const int blk = blockIdx.x;
  const int task = blk >> 1, jhalf = blk & 1;
  const int bh = task >> 4, c = task & 15;
  const int b = bh >> 3, h = bh & 7;
  const int t = threadIdx.x;
  const int wid = t >> 6, lane = t & 63;
  const int fr = lane & 15, lg = lane >> 4;
  const int jt_local = wid >> 1, half = wid & 1;
  const int jtg = jhalf*2 + jt_local;
  const int row0 = b*NS + c*CHUNK;
  const int jrow0 = row0 + jhalf*32;

  // ---- GLDS staging (all sources pre-swizzled / pre-transposed)
  {
    const int sb = wid * 64;
    {  // q hi/lo: 256 slots each
      const int s = sb + lane;
      const int r = s >> 3, bk = s & 7;
      const size_t go = (size_t)(jrow0 + r)*512 + h*64 + bk*8;
      GLDS16(qh + go, qh_s + sb*8);
      GLDS16(ql + go, ql_s + sb*8);
    }
    #pragma unroll
    for (int i = 0; i < 2; ++i) {  // k hi/lo: 512 slots each
      const int s = i*256 + sb + lane;
      const int r = s >> 3, bk = s & 7;
      const size_t go = (size_t)(row0 + r)*512 + h*64 + bk*8;
      GLDS16(kh + go, kh_s + (i*256 + sb)*8);
      GLDS16(kl + go, kl_s + (i*256 + sb)*8);
    }
    #pragma unroll
    for (int i = 0; i < 4; ++i) {  // vT, C0T: 1024 slots each (linear)
      const int s = i*256 + sb + lane;
      GLDS16(vT  + (size_t)task*8192 + s*8, vt_s + (i*256 + sb)*8);
      GLDS16(C0T + (size_t)task*8192 + s*8, c0_s + (i*256 + sb)*8);
    }
  }
  const float m0v = m0g[bh*NCHUNK + c];
  if (t < 64) {
    g_l[t]  = g_g[bh*NS + c*CHUNK + t];
    n0_l[t] = n0g[task*64 + t];
  } else if (t < 96) {
    int jl = t - 64;
    float av = a_g[bh*NS + c*CHUNK + jhalf*32 + jl];
    a_l[jl] = av;
    m_l[jl] = m_g[bh*NS + c*CHUNK + jhalf*32 + jl];
    cI_l[jl] = __expf(m0v - av);
  }
  __syncthreads();

  // ---- Phase A: QK^T (hi/lo, ~f32), mask+exp, row sums, P->bf16
  float rsum[4] = {0.f, 0.f, 0.f, 0.f};
  for (int st = half; st < 4; st += 2) {
    if (st <= jtg) {
      f32x4 sacc = {};
      #pragma unroll
      for (int kk = 0; kk < 2; ++kk) {
        const int kg = kk*4 + lg;
        const int Ra = jt_local*16 + fr;
        const int Rb = st*16 + fr;
        bf16x8 qhv = *(const bf16x8*)&qh_s[Ra*64 + ((kg ^ (Ra&7))*8)];
        bf16x8 qlv = *(const bf16x8*)&ql_s[Ra*64 + ((kg ^ (Ra&7))*8)];
        bf16x8 khv = *(const bf16x8*)&kh_s[Rb*64 + ((kg ^ (Rb&7))*8)];
        bf16x8 klv = *(const bf16x8*)&kl_s[Rb*64 + ((kg ^ (Rb&7))*8)];
        sacc = __builtin_amdgcn_mfma_f32_16x16x32_bf16(qhv, khv, sacc, 0, 0, 0);
        sacc = __builtin_amdgcn_mfma_f32_16x16x32_bf16(qhv, klv, sacc, 0, 0, 0);
        sacc = __builtin_amdgcn_mfma_f32_16x16x32_bf16(qlv, khv, sacc, 0, 0, 0);
      }
      const int s_c = st*16 + fr;
      const float gs = g_l[s_c];
      #pragma unroll
      for (int r = 0; r < 4; ++r) {
        const int jl = jt_local*16 + lg*4 + r;
        const int j_c = jhalf*32 + jl;
        float w = (s_c <= j_c) ? __expf(gs - a_l[jl]) : 0.f;
        float p = sacc[r] * w;
        rsum[r] += p;
        Ps[jl*72 + s_c] = (__bf16)p;
      }
    } else {
      #pragma unroll
      for (int r = 0; r < 4; ++r)
        Ps[(jt_local*16 + lg*4 + r)*72 + st*16 + fr] = (__bf16)0.f;
    }
  }
  #pragma unroll
  for (int r = 0; r < 4; ++r) {
    #pragma unroll
    for (int off = 1; off < 16; off <<= 1) rsum[r] += __shfl_xor(rsum[r], off, 64);
  }
  if (fr == 0) {
    #pragma unroll
    for (int r = 0; r < 4; ++r) qnA[half][jt_local*16 + lg*4 + r] = rsum[r];
  }

  // ---- inter term: acc[j][u] = q_hi . C0T, then * cI[j]
  f32x4 acc[4] = {};
  #pragma unroll
  for (int kk = 0; kk < 2; ++kk) {
    const int kg = kk*4 + lg;
    const int Ra = jt_local*16 + fr;
    bf16x8 aq = *(const bf16x8*)&qh_s[Ra*64 + ((kg ^ (Ra&7))*8)];
    #pragma unroll
    for (int nt = 0; nt < 4; ++nt) {
      const int Rb = (half*4 + nt)*16 + fr;
      bf16x8 bc = *(const bf16x8*)&c0_s[Rb*64 + ((kg ^ (Rb&7))*8)];
      acc[nt] = __builtin_amdgcn_mfma_f32_16x16x32_bf16(aq, bc, acc[nt], 0, 0, 0);
    }
  }
  {
    float ci4[4];
    #pragma unroll
    for (int r = 0; r < 4; ++r) ci4[r] = cI_l[jt_local*16 + lg*4 + r];
    #pragma unroll
    for (int nt = 0; nt < 4; ++nt)
      #pragma unroll
      for (int r = 0; r < 4; ++r) acc[nt][r] *= ci4[r];
  }
  // ---- qn_inter (half==1 waves): cI[j] * sum_d q[j][d]*n0[d]
  if (half == 1) {
    const int jl = jt_local*16 + fr;
    float s = 0.f;
    #pragma unroll
    for (int i = 0; i < 16; ++i) {
      const int d = lg*16 + i;
      const int off = jl*64 + (((d>>3) ^ (jl&7)) << 3) + (d & 7);
      float qv = (float)qh_s[off] + (float)ql_s[off];
      s += qv * n0_l[d];
    }
    s += __shfl_xor(s, 16, 64);
    s += __shfl_xor(s, 32, 64);
    if (lane < 16) qnI_l[jl] = cI_l[jl] * s;
  }
  __syncthreads();   // Ps/qnA/qnI visibility for PV + epilogue

  // ---- PV: acc += Ps . vT
  #pragma unroll
  for (int kk = 0; kk < 2; ++kk) {
    const int kg = kk*4 + lg;
    bf16x8 ap = *(const bf16x8*)&Ps[(jt_local*16 + fr)*72 + kg*8];
    #pragma unroll
    for (int nt = 0; nt < 4; ++nt) {
      const int Rb = (half*4 + nt)*16 + fr;
      bf16x8 bv = *(const bf16x8*)&vt_s[Rb*64 + ((kg ^ (Rb&7))*8)];
      acc[nt] = __builtin_amdgcn_mfma_f32_16x16x32_bf16(ap, bv, acc[nt], 0, 0, 0);
    }
  }

  // ---- epilogue part 1: denom + LN partials
  #pragma unroll
  for (int r = 0; r < 4; ++r) {
    const int jl = jt_local*16 + lg*4 + r;
    float qn = qnA[0][jl] + qnA[1][jl] + qnI_l[jl];
    float denom = fmaxf(fabsf(qn), __expf(-m_l[jl])) + 1e-6f;
    float rd = 1.f / denom;
    float s = 0.f, q2 = 0.f;
    #pragma unroll
    for (int nt = 0; nt < 4; ++nt) {
      float hv = acc[nt][r] * rd;
      acc[nt][r] = hv;
      s += hv; q2 += hv*hv;
    }
    #pragma unroll
    for (int off = 1; off < 16; off <<= 1) {
      s  += __shfl_xor(s,  off, 64);
      q2 += __shfl_xor(q2, off, 64);
    }
    if (fr == 0) { lnS[half][jl] = s; lnQ[half][jl] = q2; }
  }
  __syncthreads();

  // ---- epilogue part 2: LN + output gate (pre-computed sigmoid f16) + bf16 store
  #pragma unroll
  for (int r = 0; r < 4; ++r) {
    const int jl = jt_local*16 + lg*4 + r;
    float sm = lnS[0][jl] + lnS[1][jl];
    float sq = lnQ[0][jl] + lnQ[1][jl];
    float mu = sm * (1.f/128.f);
    float var = sq * (1.f/128.f) - mu*mu;
    float rstd = rsqrtf(var + 1e-6f);
    const int rowg = jrow0 + jl;
    #pragma unroll
    for (int nt = 0; nt < 4; ++nt) {
      const int u = (half*4 + nt)*16 + fr;
      float sg = (float)ogs[(size_t)rowg*1024 + h*DHV + u];
      float hn = (acc[nt][r] - mu) * rstd * gamma[h*DHV + u] * sg;
      hout[(size_t)rowg*NV + h*DHV + u] = (__bf16)hn;
    }
  }
}

extern "C" void kernel_launch(void* const* d_in, const int* in_sizes, int n_in,
                              void* d_out, int out_size, void* d_ws, size_t ws_size,
                              hipStream_t stream) {
  const float* x    = (const float*)d_in[0];
  const float* Wq   = (const float*)d_in[1];
  const float* Wk   = (const float*)d_in[2];
  const float* Wv   = (const float*)d_in[3];
  const float* Wog  = (const float*)d_in[4];
  const float* Wi   = (const float*)d_in[5];
  const float* bi   = (const float*)d_in[6];
  const float* Wf   = (const float*)d_in[7];
  const float* bf_  = (const float*)d_in[8];
  const float* gamma= (const float*)d_in[9];
  const float* Wout = (const float*)d_in[10];
  float* y = (float*)d_out;

  char* ws = (char*)d_ws;
  const size_t MB = 1u << 20;
  __bf16*   xb   = (__bf16*)  (ws + 0);        // 4 MB
  __bf16*   Wb   = (__bf16*)  (ws + 4*MB);     // 6 MB
  __bf16*   Wob  = (__bf16*)  (ws + 10*MB);    // 2 MB
  __bf16*   qh   = (__bf16*)  (ws + 12*MB);    // 2 MB  [2048][512] swz
  __bf16*   ql   = (__bf16*)  (ws + 14*MB);    // 2 MB
  __bf16*   kh   = (__bf16*)  (ws + 16*MB);    // 2 MB
  __bf16*   kl   = (__bf16*)  (ws + 18*MB);    // 2 MB
  __bf16*   kT   = (__bf16*)  (ws + 20*MB);    // 2 MB  [256][64][64] swz
  __bf16*   vT   = (__bf16*)  (ws + 22*MB);    // 4 MB  [256][128][64] swz
  _Float16* ogs  = (_Float16*)(ws + 26*MB);    // 4 MB  [2048][1024] sigmoid
  float*    Ut   = (float*)   (ws + 30*MB);    // 8 MB  [256][128][64]
  __bf16*   C0T  = (__bf16*)  (ws + 38*MB);    // 4 MB  [256][128][64] swz
  float*    icap = (float*)   (ws + 42*MB);
  float*    flog = (float*)   (ws + 42*MB + 64*1024);
  float*    g_g  = (float*)   (ws + 42*MB + 128*1024);
  float*    a_g  = (float*)   (ws + 42*MB + 192*1024);
  float*    m_g  = (float*)   (ws + 42*MB + 256*1024);
  float*    m0g  = (float*)   (ws + 42*MB + 320*1024);
  float*    Ung  = (float*)   (ws + 42*MB + 384*1024);
  float*    n0g  = (float*)   (ws + 42*MB + 448*1024);
  __bf16*   houtb= (__bf16*)  (ws + 44*MB);    // 4 MB

  cvt_all<<<6144, 256, 0, stream>>>(x, Wq, Wk, Wv, Wog, Wout, xb, Wb, Wob);

  gemm_proj<<<384, 256, 0, stream>>>(xb, Wb, qh, ql, kh, kl, kT, vT, ogs);

  ifgate_kernel<<<2048, 256, 0, stream>>>(x, Wi, bi, Wf, bf_, icap, flog);
  gates_kernel<<<16, 64, 0, stream>>>(icap, flog, g_g, a_g, m_g, m0g);
  u_kernel<<<256, 256, 0, stream>>>(kT, vT, g_g, a_g, Ut, Ung);
  statescan_kernel<<<32, 512, 0, stream>>>(Ut, Ung, m0g, a_g, C0T, n0g);
  intra_kernel<<<512, 256, 0, stream>>>(qh, ql, kh, kl, vT, C0T, ogs,
                                        g_g, a_g, m_g, m0g, n0g, gamma, houtb);

  gemm_bt<<<128, 256, 0, stream>>>(houtb, Wob, y, 2048, 1024, 1024, 8, 128);
}